// Round 9
// baseline (237.361 us; speedup 1.0000x reference)
//
#include <hip/hip_runtime.h>

#define GN 50000      // nodes
#define GE 800000     // edges per graph
#define HID 128
#define OUTC 64
#define NBK 196       // buckets of 256 nodes
#define NW  196       // WGs per graph in pass 1
#define EPW 4096      // edges per WG
#define PCAP 5888     // p2sort stage capacity
#define A1B 2048      // agg1 blocks

// workspace layout (float element offsets)
#define OFF_H1    0            // h1 bf16 (pre-scaled by dinv1): GN*128 ushort
#define OFF_H2    3200000      // h2 bf16 (pre-scaled by dinv2) -- aliased: pb
#define OFF_DINV1 4800000
#define OFF_DINV2 4850000
#define OFF_ROW1  4900000
#define OFF_ROW2  4950004
#define OFF_HIST  5000008
#define OFF_TOT   5076840
#define OFF_BBASE 5077232
#define OFF_BN    5077632      // 512 f: scale@0 shift@128
#define OFF_PART  5078144      // A1B*256 f
#define OFF_PARTA 5602432      // 16*256 f
#define OFF_SRC1  5606528      // 800,000 int (16B-aligned)
#define OFF_SRC2  6406528      // 800,000 int

typedef __attribute__((ext_vector_type(8))) short bf16x8;
typedef __attribute__((ext_vector_type(4))) float f32x4;

__device__ inline unsigned bf16rne(float f) {
  unsigned u = __float_as_uint(f);
  return (u + 0x7FFFu + ((u >> 16) & 1u)) >> 16;
}
__device__ inline unsigned pack2(float a, float b) {
  return bf16rne(a) | (bf16rne(b) << 16);
}
__device__ inline float bflo(unsigned w) { return __uint_as_float(w << 16); }
__device__ inline float bfhi(unsigned w) { return __uint_as_float(w & 0xFFFF0000u); }
__device__ inline float bfs(unsigned short w) { return __uint_as_float(((unsigned)w) << 16); }

// ---------------- CSR build (round-4 exact) ----------------
__global__ __launch_bounds__(256) void p1hist_kernel(const int* __restrict__ e1,
    const int* __restrict__ e2, int* __restrict__ hist) {
  __shared__ int h[NBK];
  int g = blockIdx.y, w = blockIdx.x;
  const int* dst = (g ? e2 : e1) + GE;
  for (int i = threadIdx.x; i < NBK; i += 256) h[i] = 0;
  __syncthreads();
  int i0 = w * EPW, iend = i0 + EPW; if (iend > GE) iend = GE;
  for (int i = i0 + threadIdx.x; i < iend; i += 256)
    atomicAdd(&h[dst[i] >> 8], 1);
  __syncthreads();
  int* out = hist + ((size_t)g * NW + w) * NBK;
  for (int i = threadIdx.x; i < NBK; i += 256) out[i] = h[i];
}

__global__ __launch_bounds__(256) void histscanA_kernel(int* __restrict__ hist,
    int* __restrict__ tot) {
  __shared__ int lds[256];
  int b = blockIdx.x, g = blockIdx.y, t = threadIdx.x;
  int* col = hist + (size_t)g * NW * NBK + b;
  int v = (t < NW) ? col[(size_t)t * NBK] : 0;
  lds[t] = v;
  __syncthreads();
  for (int off = 1; off < 256; off <<= 1) {
    int u = (t >= off) ? lds[t - off] : 0;
    __syncthreads();
    lds[t] += u;
    __syncthreads();
  }
  if (t < NW) col[(size_t)t * NBK] = lds[t] - v;
  if (t == NW - 1) tot[g * NBK + b] = lds[t];
}

__global__ __launch_bounds__(256) void histscanB_kernel(const int* __restrict__ tot,
    int* __restrict__ bbase) {
  __shared__ int lds[256];
  int t = threadIdx.x;
  for (int g = 0; g < 2; ++g) {
    int v = (t < NBK) ? tot[g * NBK + t] : 0;
    int orig = v;
    lds[t] = v;
    __syncthreads();
    for (int off = 1; off < 256; off <<= 1) {
      int u = (t >= off) ? lds[t - off] : 0;
      __syncthreads();
      lds[t] += u;
      __syncthreads();
    }
    if (t < NBK) bbase[g * (NBK + 1) + t] = lds[t] - orig;
    if (t == NBK - 1) bbase[g * (NBK + 1) + NBK] = lds[t];
    __syncthreads();
  }
}

__global__ __launch_bounds__(256) void p1scat_kernel(const int* __restrict__ e1,
    const int* __restrict__ e2, const int* __restrict__ hist,
    const int* __restrict__ bbase, int* __restrict__ pb1, int* __restrict__ pb2) {
  __shared__ int off[NBK];
  int g = blockIdx.y, w = blockIdx.x;
  const int* e = g ? e2 : e1;
  int* pb = g ? pb2 : pb1;
  const int* hrow = hist + ((size_t)g * NW + w) * NBK;
  const int* bb = bbase + g * (NBK + 1);
  for (int i = threadIdx.x; i < NBK; i += 256) off[i] = bb[i] + hrow[i];
  __syncthreads();
  int i0 = w * EPW, iend = i0 + EPW; if (iend > GE) iend = GE;
  for (int i = i0 + threadIdx.x; i < iend; i += 256) {
    int d = e[GE + i], s = e[i];
    int p = atomicAdd(&off[d >> 8], 1);
    pb[p] = s | ((d & 255) << 16);
  }
}

__global__ __launch_bounds__(256) void p2sort_kernel(const int* __restrict__ pb1,
    const int* __restrict__ pb2, const int* __restrict__ bbase,
    int* __restrict__ row1, int* __restrict__ row2,
    float* __restrict__ dinv1, float* __restrict__ dinv2,
    int* __restrict__ src1, int* __restrict__ src2) {
  __shared__ int stage[PCAP];
  __shared__ int lcnt[256], lc2[256], arr[256];
  __shared__ int lrow[257];
  int g = blockIdx.y, b = blockIdx.x, t = threadIdx.x;
  const int* pb = g ? pb2 : pb1;
  const int* bb = bbase + g * (NBK + 1);
  int* row = g ? row2 : row1;
  float* dinv = g ? dinv2 : dinv1;
  int* src = g ? src2 : src1;
  int lo = b << 8, hi = lo + 256; if (hi > GN) hi = GN;
  int nn = hi - lo;
  int base = bb[b], end = bb[b + 1], L = end - base;
  lcnt[t] = 0; lc2[t] = 0;
  __syncthreads();
  for (int i = base + t; i < end; i += 256)
    atomicAdd(&lcnt[((unsigned)pb[i]) >> 16], 1);
  __syncthreads();
  int v = lcnt[t];
  arr[t] = v;
  __syncthreads();
  for (int off = 1; off < 256; off <<= 1) {
    int u = (t >= off) ? arr[t - off] : 0;
    __syncthreads();
    arr[t] += u;
    __syncthreads();
  }
  lrow[t] = arr[t] - v;
  if (t == 255) lrow[256] = arr[255];
  __syncthreads();
  if (t < nn) {
    row[lo + t] = base + lrow[t];
    dinv[lo + t] = rsqrtf(1.0f + (float)lcnt[t]);
  }
  if (b == NBK - 1 && t == 0) row[GN] = end;
  if (L <= PCAP) {
    for (int i = base + t; i < end; i += 256) {
      unsigned p = (unsigned)pb[i];
      int ld = p >> 16;
      int rk = atomicAdd(&lc2[ld], 1);
      stage[lrow[ld] + rk] = (int)(p & 0xFFFFu);
    }
    __syncthreads();
    for (int i = t; i < L; i += 256) src[base + i] = stage[i];
  } else {
    for (int i = base + t; i < end; i += 256) {
      unsigned p = (unsigned)pb[i];
      int ld = p >> 16;
      int rk = atomicAdd(&lc2[ld], 1);
      src[base + lrow[ld] + rk] = (int)(p & 0xFFFFu);
    }
  }
}

// ---------------- MFMA GEMMs (round-4 exact) ----------------
__global__ __launch_bounds__(256) void gemm1_kernel(const float* __restrict__ A,
    const float* __restrict__ W1, const float* __restrict__ dinv1,
    unsigned short* __restrict__ h1u) {
  __shared__ unsigned a_lds[64 * 68];    // [m][k2] stride 68 words (136 ushort)
  __shared__ unsigned w_lds[128 * 68];   // [n][k2]
  int t = threadIdx.x;
  int row0 = blockIdx.x * 64;
  for (int i = t; i < 128 * 64; i += 256) {
    int k2 = i >> 7, n = i & 127;   // coalesced in n
    w_lds[n * 68 + k2] = pack2(W1[(2 * k2) * 128 + n], W1[(2 * k2 + 1) * 128 + n]);
  }
  for (int i = t; i < 64 * 32; i += 256) {
    int m = i >> 5, k4 = i & 31;
    int gr = row0 + m;
    float4 v = (gr < GN) ? ((const float4*)A)[(size_t)gr * 32 + k4]
                         : make_float4(0.f, 0.f, 0.f, 0.f);
    unsigned* dst = &a_lds[m * 68 + k4 * 2];
    dst[0] = pack2(v.x, v.y);
    dst[1] = pack2(v.z, v.w);
  }
  __syncthreads();
  int lane = t & 63, w = t >> 6;
  int n16 = lane & 15, quad = lane >> 4;
  int mbase = (w & 1) * 32;
  int nbase = (w >> 1) * 64;
  f32x4 acc[2][4] = {};
  const unsigned short* als = (const unsigned short*)a_lds;
  const unsigned short* wls = (const unsigned short*)w_lds;
  #pragma unroll
  for (int ks = 0; ks < 4; ++ks) {
    int k0 = ks * 32 + quad * 8;
    bf16x8 a0 = *(const bf16x8*)(als + (mbase + n16) * 136 + k0);
    bf16x8 a1 = *(const bf16x8*)(als + (mbase + 16 + n16) * 136 + k0);
    #pragma unroll
    for (int nt = 0; nt < 4; ++nt) {
      bf16x8 bf = *(const bf16x8*)(wls + (nbase + nt * 16 + n16) * 136 + k0);
      acc[0][nt] = __builtin_amdgcn_mfma_f32_16x16x32_bf16(a0, bf, acc[0][nt], 0, 0, 0);
      acc[1][nt] = __builtin_amdgcn_mfma_f32_16x16x32_bf16(a1, bf, acc[1][nt], 0, 0, 0);
    }
  }
  #pragma unroll
  for (int mt = 0; mt < 2; ++mt) {
    #pragma unroll
    for (int r = 0; r < 4; ++r) {
      int row_g = row0 + mbase + mt * 16 + quad * 4 + r;
      if (row_g < GN) {
        float dv = dinv1[row_g];
        #pragma unroll
        for (int nt = 0; nt < 4; ++nt) {
          int col = nbase + nt * 16 + n16;
          h1u[(size_t)row_g * 128 + col] = (unsigned short)bf16rne(dv * acc[mt][nt][r]);
        }
      }
    }
  }
}

__global__ __launch_bounds__(256) void gemm2_kernel(const float* __restrict__ A,
    const float* __restrict__ W2, const float* __restrict__ scale,
    const float* __restrict__ shift, const float* __restrict__ dinv2,
    unsigned short* __restrict__ h2u) {
  __shared__ unsigned a_lds[64 * 68];
  __shared__ unsigned w_lds[64 * 68];
  __shared__ float sc[128], sh[128];
  int t = threadIdx.x;
  if (t < 128) { sc[t] = scale[t]; sh[t] = shift[t]; }
  int row0 = blockIdx.x * 64;
  for (int i = t; i < 64 * 64; i += 256) {
    int k2 = i >> 6, n = i & 63;
    w_lds[n * 68 + k2] = pack2(W2[(2 * k2) * 64 + n], W2[(2 * k2 + 1) * 64 + n]);
  }
  __syncthreads();   // sc/sh + w_lds ready
  for (int i = t; i < 64 * 32; i += 256) {
    int m = i >> 5, k4 = i & 31;
    int gr = row0 + m;
    float4 v = (gr < GN) ? ((const float4*)A)[(size_t)gr * 32 + k4]
                         : make_float4(0.f, 0.f, 0.f, 0.f);
    int c = k4 * 4;
    v.x = fmaxf(fmaf(v.x, sc[c],     sh[c]),     0.f);
    v.y = fmaxf(fmaf(v.y, sc[c + 1], sh[c + 1]), 0.f);
    v.z = fmaxf(fmaf(v.z, sc[c + 2], sh[c + 2]), 0.f);
    v.w = fmaxf(fmaf(v.w, sc[c + 3], sh[c + 3]), 0.f);
    unsigned* dst = &a_lds[m * 68 + k4 * 2];
    dst[0] = pack2(v.x, v.y);
    dst[1] = pack2(v.z, v.w);
  }
  __syncthreads();
  int lane = t & 63, w = t >> 6;
  int n16 = lane & 15, quad = lane >> 4;
  f32x4 acc[4] = {};
  const unsigned short* als = (const unsigned short*)a_lds;
  const unsigned short* wls = (const unsigned short*)w_lds;
  #pragma unroll
  for (int ks = 0; ks < 4; ++ks) {
    int k0 = ks * 32 + quad * 8;
    bf16x8 af = *(const bf16x8*)(als + (w * 16 + n16) * 136 + k0);
    #pragma unroll
    for (int nt = 0; nt < 4; ++nt) {
      bf16x8 bf = *(const bf16x8*)(wls + (nt * 16 + n16) * 136 + k0);
      acc[nt] = __builtin_amdgcn_mfma_f32_16x16x32_bf16(af, bf, acc[nt], 0, 0, 0);
    }
  }
  #pragma unroll
  for (int r = 0; r < 4; ++r) {
    int row_g = row0 + w * 16 + quad * 4 + r;
    if (row_g < GN) {
      float dv = dinv2[row_g];
      #pragma unroll
      for (int nt = 0; nt < 4; ++nt) {
        int col = nt * 16 + n16;
        h2u[(size_t)row_g * 64 + col] = (unsigned short)bf16rne(dv * acc[nt][r]);
      }
    }
  }
}

// ---------------- Aggregations: 2 rows per wave, interleaved dep chains ----------------
// Same 8 wave-uniform loads in flight as the proven 8-wide form, but split across
// two independent rows so the pipeline stays full across row boundaries.
__global__ __launch_bounds__(256) void agg1_kernel(const unsigned* __restrict__ h1b,
    const int* __restrict__ row, const int* __restrict__ srcs,
    const float* __restrict__ dinv, const float* __restrict__ b1,
    float* __restrict__ hidden, float* __restrict__ part) {
  __shared__ float ps[256];
  int t = threadIdx.x;
  int lane = t & 63;
  float2 b = ((const float2*)b1)[lane];
  float sx = 0.f, sy = 0.f, qx = 0.f, qy = 0.f;
  int wid = (blockIdx.x * 256 + t) >> 6;      // 0..8191
  for (int d0 = wid * 2; d0 < GN; d0 += A1B * 4 * 2) {   // GN even -> d1 always valid
    int d1 = d0 + 1;
    float diA = dinv[d0], diB = dinv[d1];
    unsigned swA = h1b[(size_t)d0 * 64 + lane];
    unsigned swB = h1b[(size_t)d1 * 64 + lane];
    float ax = bflo(swA), ay = bfhi(swA);
    float bx = bflo(swB), by = bfhi(swB);
    int iA = row[d0], eA = row[d0 + 1];
    int iB = row[d1], eB = row[d1 + 1];
    while ((iA & 3) && iA < eA) {
      unsigned v = h1b[(size_t)srcs[iA] * 64 + lane];
      ax += bflo(v); ay += bfhi(v);
      ++iA;
    }
    while ((iB & 3) && iB < eB) {
      unsigned v = h1b[(size_t)srcs[iB] * 64 + lane];
      bx += bflo(v); by += bfhi(v);
      ++iB;
    }
    while (iA + 4 <= eA && iB + 4 <= eB) {    // joint 4+4: two independent chains
      int4 sa = *(const int4*)&srcs[iA];
      int4 sb = *(const int4*)&srcs[iB];
      unsigned v0 = h1b[(size_t)sa.x * 64 + lane], v1 = h1b[(size_t)sa.y * 64 + lane];
      unsigned v2 = h1b[(size_t)sa.z * 64 + lane], v3 = h1b[(size_t)sa.w * 64 + lane];
      unsigned u0 = h1b[(size_t)sb.x * 64 + lane], u1 = h1b[(size_t)sb.y * 64 + lane];
      unsigned u2 = h1b[(size_t)sb.z * 64 + lane], u3 = h1b[(size_t)sb.w * 64 + lane];
      ax += bflo(v0); ay += bfhi(v0);
      ax += bflo(v1); ay += bfhi(v1);
      ax += bflo(v2); ay += bfhi(v2);
      ax += bflo(v3); ay += bfhi(v3);
      bx += bflo(u0); by += bfhi(u0);
      bx += bflo(u1); by += bfhi(u1);
      bx += bflo(u2); by += bfhi(u2);
      bx += bflo(u3); by += bfhi(u3);
      iA += 4; iB += 4;
    }
    for (; iA + 8 <= eA; iA += 8) {
      int4 sa = *(const int4*)&srcs[iA];
      int4 sb = *(const int4*)&srcs[iA + 4];
      unsigned v0 = h1b[(size_t)sa.x * 64 + lane], v1 = h1b[(size_t)sa.y * 64 + lane];
      unsigned v2 = h1b[(size_t)sa.z * 64 + lane], v3 = h1b[(size_t)sa.w * 64 + lane];
      unsigned v4 = h1b[(size_t)sb.x * 64 + lane], v5 = h1b[(size_t)sb.y * 64 + lane];
      unsigned v6 = h1b[(size_t)sb.z * 64 + lane], v7 = h1b[(size_t)sb.w * 64 + lane];
      ax += bflo(v0); ay += bfhi(v0);
      ax += bflo(v1); ay += bfhi(v1);
      ax += bflo(v2); ay += bfhi(v2);
      ax += bflo(v3); ay += bfhi(v3);
      ax += bflo(v4); ay += bfhi(v4);
      ax += bflo(v5); ay += bfhi(v5);
      ax += bflo(v6); ay += bfhi(v6);
      ax += bflo(v7); ay += bfhi(v7);
    }
    if (iA + 4 <= eA) {
      int4 sa = *(const int4*)&srcs[iA];
      unsigned v0 = h1b[(size_t)sa.x * 64 + lane], v1 = h1b[(size_t)sa.y * 64 + lane];
      unsigned v2 = h1b[(size_t)sa.z * 64 + lane], v3 = h1b[(size_t)sa.w * 64 + lane];
      ax += bflo(v0); ay += bfhi(v0);
      ax += bflo(v1); ay += bfhi(v1);
      ax += bflo(v2); ay += bfhi(v2);
      ax += bflo(v3); ay += bfhi(v3);
      iA += 4;
    }
    for (; iA < eA; ++iA) {
      unsigned v = h1b[(size_t)srcs[iA] * 64 + lane];
      ax += bflo(v); ay += bfhi(v);
    }
    for (; iB + 8 <= eB; iB += 8) {
      int4 sa = *(const int4*)&srcs[iB];
      int4 sb = *(const int4*)&srcs[iB + 4];
      unsigned v0 = h1b[(size_t)sa.x * 64 + lane], v1 = h1b[(size_t)sa.y * 64 + lane];
      unsigned v2 = h1b[(size_t)sa.z * 64 + lane], v3 = h1b[(size_t)sa.w * 64 + lane];
      unsigned v4 = h1b[(size_t)sb.x * 64 + lane], v5 = h1b[(size_t)sb.y * 64 + lane];
      unsigned v6 = h1b[(size_t)sb.z * 64 + lane], v7 = h1b[(size_t)sb.w * 64 + lane];
      bx += bflo(v0); by += bfhi(v0);
      bx += bflo(v1); by += bfhi(v1);
      bx += bflo(v2); by += bfhi(v2);
      bx += bflo(v3); by += bfhi(v3);
      bx += bflo(v4); by += bfhi(v4);
      bx += bflo(v5); by += bfhi(v5);
      bx += bflo(v6); by += bfhi(v6);
      bx += bflo(v7); by += bfhi(v7);
    }
    if (iB + 4 <= eB) {
      int4 sa = *(const int4*)&srcs[iB];
      unsigned v0 = h1b[(size_t)sa.x * 64 + lane], v1 = h1b[(size_t)sa.y * 64 + lane];
      unsigned v2 = h1b[(size_t)sa.z * 64 + lane], v3 = h1b[(size_t)sa.w * 64 + lane];
      bx += bflo(v0); by += bfhi(v0);
      bx += bflo(v1); by += bfhi(v1);
      bx += bflo(v2); by += bfhi(v2);
      bx += bflo(v3); by += bfhi(v3);
      iB += 4;
    }
    for (; iB < eB; ++iB) {
      unsigned v = h1b[(size_t)srcs[iB] * 64 + lane];
      bx += bflo(v); by += bfhi(v);
    }
    float ox = ax * diA + b.x, oy = ay * diA + b.y;
    ((float2*)(hidden + (size_t)d0 * 128))[lane] = make_float2(ox, oy);
    sx += ox; sy += oy; qx += ox * ox; qy += oy * oy;
    float px = bx * diB + b.x, py = by * diB + b.y;
    ((float2*)(hidden + (size_t)d1 * 128))[lane] = make_float2(px, py);
    sx += px; sy += py; qx += px * px; qy += py * py;
  }
  float* pout = part + (size_t)blockIdx.x * 256;
  ps[t] = sx; __syncthreads();
  if (t < 64) pout[2 * t] = ps[t] + ps[t + 64] + ps[t + 128] + ps[t + 192];
  __syncthreads();
  ps[t] = sy; __syncthreads();
  if (t < 64) pout[2 * t + 1] = ps[t] + ps[t + 64] + ps[t + 128] + ps[t + 192];
  __syncthreads();
  ps[t] = qx; __syncthreads();
  if (t < 64) pout[128 + 2 * t] = ps[t] + ps[t + 64] + ps[t + 128] + ps[t + 192];
  __syncthreads();
  ps[t] = qy; __syncthreads();
  if (t < 64) pout[128 + 2 * t + 1] = ps[t] + ps[t + 64] + ps[t + 128] + ps[t + 192];
}

__global__ __launch_bounds__(256) void bn_reduceA_kernel(const float* __restrict__ part,
    float* __restrict__ partA) {
  int r = blockIdx.x, t = threadIdx.x;
  float s = 0.f;
  for (int k = 0; k < A1B / 16; ++k)
    s += part[((size_t)r * (A1B / 16) + k) * 256 + t];
  partA[r * 256 + t] = s;
}

__global__ __launch_bounds__(128) void bn_final_kernel(const float* __restrict__ partA,
    const float* __restrict__ gamma, const float* __restrict__ beta,
    float* __restrict__ scale, float* __restrict__ shift) {
  int c = threadIdx.x;
  float S = 0.f, Q = 0.f;
  for (int r = 0; r < 16; ++r) {
    S += partA[r * 256 + c];
    Q += partA[r * 256 + 128 + c];
  }
  float mean = S * (1.0f / GN);
  float var = Q * (1.0f / GN) - mean * mean;
  float istd = rsqrtf(var + 1e-5f);
  float g = gamma[c] * istd;
  scale[c] = g;
  shift[c] = beta[c] - mean * g;
}

// agg2: two rows per wave, interleaved chains (half the waves, same MLP).
__global__ __launch_bounds__(256) void agg2_kernel(const unsigned short* __restrict__ h2b,
    const int* __restrict__ row, const int* __restrict__ srcs,
    const float* __restrict__ dinv, const float* __restrict__ b2,
    float* __restrict__ out) {
  int wv = (blockIdx.x * 256 + threadIdx.x) >> 6;
  int lane = threadIdx.x & 63;
  if (wv >= GN / 2) return;
  int d0 = wv * 2, d1 = d0 + 1;
  float accA = bfs(h2b[(size_t)d0 * 64 + lane]);
  float accB = bfs(h2b[(size_t)d1 * 64 + lane]);
  int iA = row[d0], eA = row[d0 + 1];
  int iB = row[d1], eB = row[d1 + 1];
  while ((iA & 3) && iA < eA) {
    accA += bfs(h2b[(size_t)srcs[iA] * 64 + lane]);
    ++iA;
  }
  while ((iB & 3) && iB < eB) {
    accB += bfs(h2b[(size_t)srcs[iB] * 64 + lane]);
    ++iB;
  }
  while (iA + 4 <= eA && iB + 4 <= eB) {
    int4 sa = *(const int4*)&srcs[iA];
    int4 sb = *(const int4*)&srcs[iB];
    float v0 = bfs(h2b[(size_t)sa.x * 64 + lane]), v1 = bfs(h2b[(size_t)sa.y * 64 + lane]);
    float v2 = bfs(h2b[(size_t)sa.z * 64 + lane]), v3 = bfs(h2b[(size_t)sa.w * 64 + lane]);
    float u0 = bfs(h2b[(size_t)sb.x * 64 + lane]), u1 = bfs(h2b[(size_t)sb.y * 64 + lane]);
    float u2 = bfs(h2b[(size_t)sb.z * 64 + lane]), u3 = bfs(h2b[(size_t)sb.w * 64 + lane]);
    accA += v0 + v1 + v2 + v3;
    accB += u0 + u1 + u2 + u3;
    iA += 4; iB += 4;
  }
  for (; iA + 8 <= eA; iA += 8) {
    int4 sa = *(const int4*)&srcs[iA];
    int4 sb = *(const int4*)&srcs[iA + 4];
    float v0 = bfs(h2b[(size_t)sa.x * 64 + lane]), v1 = bfs(h2b[(size_t)sa.y * 64 + lane]);
    float v2 = bfs(h2b[(size_t)sa.z * 64 + lane]), v3 = bfs(h2b[(size_t)sa.w * 64 + lane]);
    float v4 = bfs(h2b[(size_t)sb.x * 64 + lane]), v5 = bfs(h2b[(size_t)sb.y * 64 + lane]);
    float v6 = bfs(h2b[(size_t)sb.z * 64 + lane]), v7 = bfs(h2b[(size_t)sb.w * 64 + lane]);
    accA += v0 + v1 + v2 + v3 + v4 + v5 + v6 + v7;
  }
  if (iA + 4 <= eA) {
    int4 sa = *(const int4*)&srcs[iA];
    accA += bfs(h2b[(size_t)sa.x * 64 + lane]) + bfs(h2b[(size_t)sa.y * 64 + lane])
          + bfs(h2b[(size_t)sa.z * 64 + lane]) + bfs(h2b[(size_t)sa.w * 64 + lane]);
    iA += 4;
  }
  for (; iA < eA; ++iA)
    accA += bfs(h2b[(size_t)srcs[iA] * 64 + lane]);
  for (; iB + 8 <= eB; iB += 8) {
    int4 sa = *(const int4*)&srcs[iB];
    int4 sb = *(const int4*)&srcs[iB + 4];
    float v0 = bfs(h2b[(size_t)sa.x * 64 + lane]), v1 = bfs(h2b[(size_t)sa.y * 64 + lane]);
    float v2 = bfs(h2b[(size_t)sa.z * 64 + lane]), v3 = bfs(h2b[(size_t)sa.w * 64 + lane]);
    float v4 = bfs(h2b[(size_t)sb.x * 64 + lane]), v5 = bfs(h2b[(size_t)sb.y * 64 + lane]);
    float v6 = bfs(h2b[(size_t)sb.z * 64 + lane]), v7 = bfs(h2b[(size_t)sb.w * 64 + lane]);
    accB += v0 + v1 + v2 + v3 + v4 + v5 + v6 + v7;
  }
  if (iB + 4 <= eB) {
    int4 sa = *(const int4*)&srcs[iB];
    accB += bfs(h2b[(size_t)sa.x * 64 + lane]) + bfs(h2b[(size_t)sa.y * 64 + lane])
          + bfs(h2b[(size_t)sa.z * 64 + lane]) + bfs(h2b[(size_t)sa.w * 64 + lane]);
    iB += 4;
  }
  for (; iB < eB; ++iB)
    accB += bfs(h2b[(size_t)srcs[iB] * 64 + lane]);
  out[(size_t)d0 * 64 + lane] = accA * dinv[d0] + b2[lane];
  out[(size_t)d1 * 64 + lane] = accB * dinv[d1] + b2[lane];
}

extern "C" void kernel_launch(void* const* d_in, const int* in_sizes, int n_in,
                              void* d_out, int out_size, void* d_ws, size_t ws_size,
                              hipStream_t stream) {
  const float* x     = (const float*)d_in[0];
  const int*   e1    = (const int*)d_in[1];
  const int*   e2    = (const int*)d_in[2];
  const float* W1    = (const float*)d_in[3];
  const float* b1    = (const float*)d_in[4];
  const float* gamma = (const float*)d_in[5];
  const float* beta  = (const float*)d_in[6];
  const float* W2    = (const float*)d_in[7];
  const float* b2    = (const float*)d_in[8];

  float* out    = (float*)d_out;               // [N,64]
  float* hidden = out + (size_t)GN * OUTC;     // [N,128]

  float*          ws    = (float*)d_ws;
  unsigned*       h1b   = (unsigned*)(ws + OFF_H1);
  unsigned*       h2b   = (unsigned*)(ws + OFF_H2);
  float*          dinv1 = ws + OFF_DINV1;
  float*          dinv2 = ws + OFF_DINV2;
  int*            row1  = (int*)(ws + OFF_ROW1);
  int*            row2  = (int*)(ws + OFF_ROW2);
  int*            hist  = (int*)(ws + OFF_HIST);
  int*            tot   = (int*)(ws + OFF_TOT);
  int*            bbase = (int*)(ws + OFF_BBASE);
  float*          bnbuf = ws + OFF_BN;
  float*          part  = ws + OFF_PART;
  float*          partA = ws + OFF_PARTA;
  int*            src1  = (int*)(ws + OFF_SRC1);
  int*            src2  = (int*)(ws + OFF_SRC2);
  int*            pb1   = (int*)h2b;
  int*            pb2   = pb1 + GE;

  p1hist_kernel<<<dim3(NW, 2), 256, 0, stream>>>(e1, e2, hist);
  histscanA_kernel<<<dim3(NBK, 2), 256, 0, stream>>>(hist, tot);
  histscanB_kernel<<<1, 256, 0, stream>>>(tot, bbase);
  p1scat_kernel<<<dim3(NW, 2), 256, 0, stream>>>(e1, e2, hist, bbase, pb1, pb2);
  p2sort_kernel<<<dim3(NBK, 2), 256, 0, stream>>>(pb1, pb2, bbase,
                                                  row1, row2, dinv1, dinv2, src1, src2);

  gemm1_kernel<<<(GN + 63) / 64, 256, 0, stream>>>(x, W1, dinv1,
                                                   (unsigned short*)h1b);
  agg1_kernel<<<A1B, 256, 0, stream>>>(h1b, row1, src1, dinv1, b1, hidden, part);

  bn_reduceA_kernel<<<16, 256, 0, stream>>>(part, partA);
  bn_final_kernel<<<1, 128, 0, stream>>>(partA, gamma, beta, bnbuf, bnbuf + 128);

  gemm2_kernel<<<(GN + 63) / 64, 256, 0, stream>>>(hidden, W2, bnbuf, bnbuf + 128,
                                                   dinv2, (unsigned short*)h2b);
  agg2_kernel<<<((GN / 2) * 64 + 255) / 256, 256, 0, stream>>>(
      (const unsigned short*)h2b, row2, src2, dinv2, b2, out);
}

// Round 10
// 227.591 us; speedup vs baseline: 1.0429x; 1.0429x over previous
//
#include <hip/hip_runtime.h>

#define GN 50000      // nodes
#define GE 800000     // edges per graph
#define HID 128
#define OUTC 64
#define NBK 196       // buckets of 256 nodes
#define NW  196       // WGs per graph in pass 1
#define EPW 4096      // edges per WG
#define PCAP 5888     // p2sort stage capacity
#define A1B 2048      // agg1 blocks

// workspace layout (float element offsets)
#define OFF_H1    0            // h1 bf16 (pre-scaled by dinv1): GN*128 ushort
#define OFF_H2    3200000      // h2 bf16 (pre-scaled by dinv2) -- aliased: pb
#define OFF_DINV1 4800000
#define OFF_DINV2 4850000
#define OFF_ROW1  4900000
#define OFF_ROW2  4950004
#define OFF_HIST  5000008      // 76832 ints; dead after p1scat -> partA aliases here
#define OFF_TOT   5076840
#define OFF_BBASE 5077232
#define OFF_BN    5077632      // 512 f: scale@0 shift@128
#define OFF_PART  5078144      // A1B*256 f
#define OFF_SRC1  5606528      // 800,000 int (16B-aligned)
#define OFF_SRC2  6406528      // 800,000 int

typedef __attribute__((ext_vector_type(8))) short bf16x8;
typedef __attribute__((ext_vector_type(4))) float f32x4;

__device__ inline unsigned bf16rne(float f) {
  unsigned u = __float_as_uint(f);
  return (u + 0x7FFFu + ((u >> 16) & 1u)) >> 16;
}
__device__ inline unsigned pack2(float a, float b) {
  return bf16rne(a) | (bf16rne(b) << 16);
}
__device__ inline float bflo(unsigned w) { return __uint_as_float(w << 16); }
__device__ inline float bfhi(unsigned w) { return __uint_as_float(w & 0xFFFF0000u); }
__device__ inline float bfs(unsigned short w) { return __uint_as_float(((unsigned)w) << 16); }

// ---------------- CSR build (int4-vectorized edge reads) ----------------
__global__ __launch_bounds__(256) void p1hist_kernel(const int* __restrict__ e1,
    const int* __restrict__ e2, int* __restrict__ hist) {
  __shared__ int h[NBK];
  int g = blockIdx.y, w = blockIdx.x;
  const int* dst = (g ? e2 : e1) + GE;
  for (int i = threadIdx.x; i < NBK; i += 256) h[i] = 0;
  __syncthreads();
  int i0 = w * EPW, iend = i0 + EPW; if (iend > GE) iend = GE;
  for (int i = i0 + threadIdx.x * 4; i < iend; i += 1024) {   // 16B/lane, 4 edges
    int4 d4 = *(const int4*)&dst[i];
    atomicAdd(&h[d4.x >> 8], 1);
    atomicAdd(&h[d4.y >> 8], 1);
    atomicAdd(&h[d4.z >> 8], 1);
    atomicAdd(&h[d4.w >> 8], 1);
  }
  __syncthreads();
  int* out = hist + ((size_t)g * NW + w) * NBK;
  for (int i = threadIdx.x; i < NBK; i += 256) out[i] = h[i];
}

__global__ __launch_bounds__(256) void histscanA_kernel(int* __restrict__ hist,
    int* __restrict__ tot) {
  __shared__ int lds[256];
  int b = blockIdx.x, g = blockIdx.y, t = threadIdx.x;
  int* col = hist + (size_t)g * NW * NBK + b;
  int v = (t < NW) ? col[(size_t)t * NBK] : 0;
  lds[t] = v;
  __syncthreads();
  for (int off = 1; off < 256; off <<= 1) {
    int u = (t >= off) ? lds[t - off] : 0;
    __syncthreads();
    lds[t] += u;
    __syncthreads();
  }
  if (t < NW) col[(size_t)t * NBK] = lds[t] - v;
  if (t == NW - 1) tot[g * NBK + b] = lds[t];
}

__global__ __launch_bounds__(256) void histscanB_kernel(const int* __restrict__ tot,
    int* __restrict__ bbase) {
  __shared__ int lds[256];
  int t = threadIdx.x;
  for (int g = 0; g < 2; ++g) {
    int v = (t < NBK) ? tot[g * NBK + t] : 0;
    int orig = v;
    lds[t] = v;
    __syncthreads();
    for (int off = 1; off < 256; off <<= 1) {
      int u = (t >= off) ? lds[t - off] : 0;
      __syncthreads();
      lds[t] += u;
      __syncthreads();
    }
    if (t < NBK) bbase[g * (NBK + 1) + t] = lds[t] - orig;
    if (t == NBK - 1) bbase[g * (NBK + 1) + NBK] = lds[t];
    __syncthreads();
  }
}

__global__ __launch_bounds__(256) void p1scat_kernel(const int* __restrict__ e1,
    const int* __restrict__ e2, const int* __restrict__ hist,
    const int* __restrict__ bbase, int* __restrict__ pb1, int* __restrict__ pb2) {
  __shared__ int off[NBK];
  int g = blockIdx.y, w = blockIdx.x;
  const int* e = g ? e2 : e1;
  int* pb = g ? pb2 : pb1;
  const int* hrow = hist + ((size_t)g * NW + w) * NBK;
  const int* bb = bbase + g * (NBK + 1);
  for (int i = threadIdx.x; i < NBK; i += 256) off[i] = bb[i] + hrow[i];
  __syncthreads();
  int i0 = w * EPW, iend = i0 + EPW; if (iend > GE) iend = GE;
  for (int i = i0 + threadIdx.x * 4; i < iend; i += 1024) {   // 16B/lane src + dst
    int4 s4 = *(const int4*)&e[i];
    int4 d4 = *(const int4*)&e[GE + i];
    int p0 = atomicAdd(&off[d4.x >> 8], 1);
    pb[p0] = s4.x | ((d4.x & 255) << 16);
    int p1 = atomicAdd(&off[d4.y >> 8], 1);
    pb[p1] = s4.y | ((d4.y & 255) << 16);
    int p2 = atomicAdd(&off[d4.z >> 8], 1);
    pb[p2] = s4.z | ((d4.z & 255) << 16);
    int p3 = atomicAdd(&off[d4.w >> 8], 1);
    pb[p3] = s4.w | ((d4.w & 255) << 16);
  }
}

__global__ __launch_bounds__(256) void p2sort_kernel(const int* __restrict__ pb1,
    const int* __restrict__ pb2, const int* __restrict__ bbase,
    int* __restrict__ row1, int* __restrict__ row2,
    float* __restrict__ dinv1, float* __restrict__ dinv2,
    int* __restrict__ src1, int* __restrict__ src2) {
  __shared__ int stage[PCAP];
  __shared__ int lcnt[256], lc2[256], arr[256];
  __shared__ int lrow[257];
  int g = blockIdx.y, b = blockIdx.x, t = threadIdx.x;
  const int* pb = g ? pb2 : pb1;
  const int* bb = bbase + g * (NBK + 1);
  int* row = g ? row2 : row1;
  float* dinv = g ? dinv2 : dinv1;
  int* src = g ? src2 : src1;
  int lo = b << 8, hi = lo + 256; if (hi > GN) hi = GN;
  int nn = hi - lo;
  int base = bb[b], end = bb[b + 1], L = end - base;
  lcnt[t] = 0; lc2[t] = 0;
  __syncthreads();
  for (int i = base + t; i < end; i += 256)
    atomicAdd(&lcnt[((unsigned)pb[i]) >> 16], 1);
  __syncthreads();
  int v = lcnt[t];
  arr[t] = v;
  __syncthreads();
  for (int off = 1; off < 256; off <<= 1) {
    int u = (t >= off) ? arr[t - off] : 0;
    __syncthreads();
    arr[t] += u;
    __syncthreads();
  }
  lrow[t] = arr[t] - v;
  if (t == 255) lrow[256] = arr[255];
  __syncthreads();
  if (t < nn) {
    row[lo + t] = base + lrow[t];
    dinv[lo + t] = rsqrtf(1.0f + (float)lcnt[t]);
  }
  if (b == NBK - 1 && t == 0) row[GN] = end;
  if (L <= PCAP) {
    for (int i = base + t; i < end; i += 256) {
      unsigned p = (unsigned)pb[i];
      int ld = p >> 16;
      int rk = atomicAdd(&lc2[ld], 1);
      stage[lrow[ld] + rk] = (int)(p & 0xFFFFu);
    }
    __syncthreads();
    for (int i = t; i < L; i += 256) src[base + i] = stage[i];
  } else {
    for (int i = base + t; i < end; i += 256) {
      unsigned p = (unsigned)pb[i];
      int ld = p >> 16;
      int rk = atomicAdd(&lc2[ld], 1);
      src[base + lrow[ld] + rk] = (int)(p & 0xFFFFu);
    }
  }
}

// ---------------- MFMA GEMMs (round-4 exact) ----------------
__global__ __launch_bounds__(256) void gemm1_kernel(const float* __restrict__ A,
    const float* __restrict__ W1, const float* __restrict__ dinv1,
    unsigned short* __restrict__ h1u) {
  __shared__ unsigned a_lds[64 * 68];    // [m][k2] stride 68 words (136 ushort)
  __shared__ unsigned w_lds[128 * 68];   // [n][k2]
  int t = threadIdx.x;
  int row0 = blockIdx.x * 64;
  for (int i = t; i < 128 * 64; i += 256) {
    int k2 = i >> 7, n = i & 127;   // coalesced in n
    w_lds[n * 68 + k2] = pack2(W1[(2 * k2) * 128 + n], W1[(2 * k2 + 1) * 128 + n]);
  }
  for (int i = t; i < 64 * 32; i += 256) {
    int m = i >> 5, k4 = i & 31;
    int gr = row0 + m;
    float4 v = (gr < GN) ? ((const float4*)A)[(size_t)gr * 32 + k4]
                         : make_float4(0.f, 0.f, 0.f, 0.f);
    unsigned* dst = &a_lds[m * 68 + k4 * 2];
    dst[0] = pack2(v.x, v.y);
    dst[1] = pack2(v.z, v.w);
  }
  __syncthreads();
  int lane = t & 63, w = t >> 6;
  int n16 = lane & 15, quad = lane >> 4;
  int mbase = (w & 1) * 32;
  int nbase = (w >> 1) * 64;
  f32x4 acc[2][4] = {};
  const unsigned short* als = (const unsigned short*)a_lds;
  const unsigned short* wls = (const unsigned short*)w_lds;
  #pragma unroll
  for (int ks = 0; ks < 4; ++ks) {
    int k0 = ks * 32 + quad * 8;
    bf16x8 a0 = *(const bf16x8*)(als + (mbase + n16) * 136 + k0);
    bf16x8 a1 = *(const bf16x8*)(als + (mbase + 16 + n16) * 136 + k0);
    #pragma unroll
    for (int nt = 0; nt < 4; ++nt) {
      bf16x8 bf = *(const bf16x8*)(wls + (nbase + nt * 16 + n16) * 136 + k0);
      acc[0][nt] = __builtin_amdgcn_mfma_f32_16x16x32_bf16(a0, bf, acc[0][nt], 0, 0, 0);
      acc[1][nt] = __builtin_amdgcn_mfma_f32_16x16x32_bf16(a1, bf, acc[1][nt], 0, 0, 0);
    }
  }
  #pragma unroll
  for (int mt = 0; mt < 2; ++mt) {
    #pragma unroll
    for (int r = 0; r < 4; ++r) {
      int row_g = row0 + mbase + mt * 16 + quad * 4 + r;
      if (row_g < GN) {
        float dv = dinv1[row_g];
        #pragma unroll
        for (int nt = 0; nt < 4; ++nt) {
          int col = nbase + nt * 16 + n16;
          h1u[(size_t)row_g * 128 + col] = (unsigned short)bf16rne(dv * acc[mt][nt][r]);
        }
      }
    }
  }
}

__global__ __launch_bounds__(256) void gemm2_kernel(const float* __restrict__ A,
    const float* __restrict__ W2, const float* __restrict__ scale,
    const float* __restrict__ shift, const float* __restrict__ dinv2,
    unsigned short* __restrict__ h2u) {
  __shared__ unsigned a_lds[64 * 68];
  __shared__ unsigned w_lds[64 * 68];
  __shared__ float sc[128], sh[128];
  int t = threadIdx.x;
  if (t < 128) { sc[t] = scale[t]; sh[t] = shift[t]; }
  int row0 = blockIdx.x * 64;
  for (int i = t; i < 64 * 64; i += 256) {
    int k2 = i >> 6, n = i & 63;
    w_lds[n * 68 + k2] = pack2(W2[(2 * k2) * 64 + n], W2[(2 * k2 + 1) * 64 + n]);
  }
  __syncthreads();   // sc/sh + w_lds ready
  for (int i = t; i < 64 * 32; i += 256) {
    int m = i >> 5, k4 = i & 31;
    int gr = row0 + m;
    float4 v = (gr < GN) ? ((const float4*)A)[(size_t)gr * 32 + k4]
                         : make_float4(0.f, 0.f, 0.f, 0.f);
    int c = k4 * 4;
    v.x = fmaxf(fmaf(v.x, sc[c],     sh[c]),     0.f);
    v.y = fmaxf(fmaf(v.y, sc[c + 1], sh[c + 1]), 0.f);
    v.z = fmaxf(fmaf(v.z, sc[c + 2], sh[c + 2]), 0.f);
    v.w = fmaxf(fmaf(v.w, sc[c + 3], sh[c + 3]), 0.f);
    unsigned* dst = &a_lds[m * 68 + k4 * 2];
    dst[0] = pack2(v.x, v.y);
    dst[1] = pack2(v.z, v.w);
  }
  __syncthreads();
  int lane = t & 63, w = t >> 6;
  int n16 = lane & 15, quad = lane >> 4;
  f32x4 acc[4] = {};
  const unsigned short* als = (const unsigned short*)a_lds;
  const unsigned short* wls = (const unsigned short*)w_lds;
  #pragma unroll
  for (int ks = 0; ks < 4; ++ks) {
    int k0 = ks * 32 + quad * 8;
    bf16x8 af = *(const bf16x8*)(als + (w * 16 + n16) * 136 + k0);
    #pragma unroll
    for (int nt = 0; nt < 4; ++nt) {
      bf16x8 bf = *(const bf16x8*)(wls + (nt * 16 + n16) * 136 + k0);
      acc[nt] = __builtin_amdgcn_mfma_f32_16x16x32_bf16(af, bf, acc[nt], 0, 0, 0);
    }
  }
  #pragma unroll
  for (int r = 0; r < 4; ++r) {
    int row_g = row0 + w * 16 + quad * 4 + r;
    if (row_g < GN) {
      float dv = dinv2[row_g];
      #pragma unroll
      for (int nt = 0; nt < 4; ++nt) {
        int col = nt * 16 + n16;
        h2u[(size_t)row_g * 64 + col] = (unsigned short)bf16rne(dv * acc[nt][r]);
      }
    }
  }
}

// ---------------- Aggregations (round-4 exact: 8-wide wave-uniform gather) ----------------
__global__ __launch_bounds__(256) void agg1_kernel(const unsigned* __restrict__ h1b,
    const int* __restrict__ row, const int* __restrict__ srcs,
    const float* __restrict__ dinv, const float* __restrict__ b1,
    float* __restrict__ hidden, float* __restrict__ part) {
  __shared__ float ps[256];
  int t = threadIdx.x;
  int lane = t & 63;
  float2 b = ((const float2*)b1)[lane];
  float sx = 0.f, sy = 0.f, qx = 0.f, qy = 0.f;
  int wid = (blockIdx.x * 256 + t) >> 6;
  for (int d = wid; d < GN; d += A1B * 4) {
    float di = dinv[d];
    unsigned sw = h1b[(size_t)d * 64 + lane];
    float ax = bflo(sw), ay = bfhi(sw);
    int e0 = row[d], e1 = row[d + 1];
    int i = e0;
    while ((i & 3) && i < e1) {
      unsigned v = h1b[(size_t)srcs[i] * 64 + lane];
      ax += bflo(v); ay += bfhi(v);
      ++i;
    }
    for (; i + 8 <= e1; i += 8) {
      int4 sa = *(const int4*)&srcs[i];
      int4 sb = *(const int4*)&srcs[i + 4];
      unsigned v0 = h1b[(size_t)sa.x * 64 + lane], v1 = h1b[(size_t)sa.y * 64 + lane];
      unsigned v2 = h1b[(size_t)sa.z * 64 + lane], v3 = h1b[(size_t)sa.w * 64 + lane];
      unsigned v4 = h1b[(size_t)sb.x * 64 + lane], v5 = h1b[(size_t)sb.y * 64 + lane];
      unsigned v6 = h1b[(size_t)sb.z * 64 + lane], v7 = h1b[(size_t)sb.w * 64 + lane];
      ax += bflo(v0); ay += bfhi(v0);
      ax += bflo(v1); ay += bfhi(v1);
      ax += bflo(v2); ay += bfhi(v2);
      ax += bflo(v3); ay += bfhi(v3);
      ax += bflo(v4); ay += bfhi(v4);
      ax += bflo(v5); ay += bfhi(v5);
      ax += bflo(v6); ay += bfhi(v6);
      ax += bflo(v7); ay += bfhi(v7);
    }
    if (i + 4 <= e1) {
      int4 sa = *(const int4*)&srcs[i];
      unsigned v0 = h1b[(size_t)sa.x * 64 + lane], v1 = h1b[(size_t)sa.y * 64 + lane];
      unsigned v2 = h1b[(size_t)sa.z * 64 + lane], v3 = h1b[(size_t)sa.w * 64 + lane];
      ax += bflo(v0); ay += bfhi(v0);
      ax += bflo(v1); ay += bfhi(v1);
      ax += bflo(v2); ay += bfhi(v2);
      ax += bflo(v3); ay += bfhi(v3);
      i += 4;
    }
    for (; i < e1; ++i) {
      unsigned v = h1b[(size_t)srcs[i] * 64 + lane];
      ax += bflo(v); ay += bfhi(v);
    }
    float ox = ax * di + b.x, oy = ay * di + b.y;
    float2 o; o.x = ox; o.y = oy;
    ((float2*)(hidden + (size_t)d * 128))[lane] = o;
    sx += ox; sy += oy; qx += ox * ox; qy += oy * oy;
  }
  float* pout = part + (size_t)blockIdx.x * 256;
  ps[t] = sx; __syncthreads();
  if (t < 64) pout[2 * t] = ps[t] + ps[t + 64] + ps[t + 128] + ps[t + 192];
  __syncthreads();
  ps[t] = sy; __syncthreads();
  if (t < 64) pout[2 * t + 1] = ps[t] + ps[t + 64] + ps[t + 128] + ps[t + 192];
  __syncthreads();
  ps[t] = qx; __syncthreads();
  if (t < 64) pout[128 + 2 * t] = ps[t] + ps[t + 64] + ps[t + 128] + ps[t + 192];
  __syncthreads();
  ps[t] = qy; __syncthreads();
  if (t < 64) pout[128 + 2 * t + 1] = ps[t] + ps[t + 64] + ps[t + 128] + ps[t + 192];
}

// 64 blocks x 32 rows (was 16 x 128): 4x the parallelism for the 2 MB reduce.
__global__ __launch_bounds__(256) void bn_reduceA_kernel(const float* __restrict__ part,
    float* __restrict__ partA) {
  int r = blockIdx.x, t = threadIdx.x;
  float s = 0.f;
  for (int k = 0; k < A1B / 64; ++k)
    s += part[((size_t)r * (A1B / 64) + k) * 256 + t];
  partA[r * 256 + t] = s;
}

__global__ __launch_bounds__(128) void bn_final_kernel(const float* __restrict__ partA,
    const float* __restrict__ gamma, const float* __restrict__ beta,
    float* __restrict__ scale, float* __restrict__ shift) {
  int c = threadIdx.x;
  float S = 0.f, Q = 0.f;
  for (int r = 0; r < 64; ++r) {
    S += partA[r * 256 + c];
    Q += partA[r * 256 + 128 + c];
  }
  float mean = S * (1.0f / GN);
  float var = Q * (1.0f / GN) - mean * mean;
  float istd = rsqrtf(var + 1e-5f);
  float g = gamma[c] * istd;
  scale[c] = g;
  shift[c] = beta[c] - mean * g;
}

__global__ __launch_bounds__(256) void agg2_kernel(const unsigned short* __restrict__ h2b,
    const int* __restrict__ row, const int* __restrict__ srcs,
    const float* __restrict__ dinv, const float* __restrict__ b2,
    float* __restrict__ out) {
  int wave = (blockIdx.x * 256 + threadIdx.x) >> 6;
  int lane = threadIdx.x & 63;
  if (wave >= GN) return;
  int d = wave;
  float di = dinv[d];
  float acc = bfs(h2b[(size_t)d * 64 + lane]);
  int e0 = row[d], e1 = row[d + 1];
  int i = e0;
  while ((i & 3) && i < e1) {
    acc += bfs(h2b[(size_t)srcs[i] * 64 + lane]);
    ++i;
  }
  for (; i + 8 <= e1; i += 8) {
    int4 sa = *(const int4*)&srcs[i];
    int4 sb = *(const int4*)&srcs[i + 4];
    float v0 = bfs(h2b[(size_t)sa.x * 64 + lane]), v1 = bfs(h2b[(size_t)sa.y * 64 + lane]);
    float v2 = bfs(h2b[(size_t)sa.z * 64 + lane]), v3 = bfs(h2b[(size_t)sa.w * 64 + lane]);
    float v4 = bfs(h2b[(size_t)sb.x * 64 + lane]), v5 = bfs(h2b[(size_t)sb.y * 64 + lane]);
    float v6 = bfs(h2b[(size_t)sb.z * 64 + lane]), v7 = bfs(h2b[(size_t)sb.w * 64 + lane]);
    acc += v0 + v1 + v2 + v3 + v4 + v5 + v6 + v7;
  }
  if (i + 4 <= e1) {
    int4 sa = *(const int4*)&srcs[i];
    acc += bfs(h2b[(size_t)sa.x * 64 + lane]) + bfs(h2b[(size_t)sa.y * 64 + lane])
         + bfs(h2b[(size_t)sa.z * 64 + lane]) + bfs(h2b[(size_t)sa.w * 64 + lane]);
    i += 4;
  }
  for (; i < e1; ++i)
    acc += bfs(h2b[(size_t)srcs[i] * 64 + lane]);
  out[(size_t)d * 64 + lane] = acc * di + b2[lane];
}

extern "C" void kernel_launch(void* const* d_in, const int* in_sizes, int n_in,
                              void* d_out, int out_size, void* d_ws, size_t ws_size,
                              hipStream_t stream) {
  const float* x     = (const float*)d_in[0];
  const int*   e1    = (const int*)d_in[1];
  const int*   e2    = (const int*)d_in[2];
  const float* W1    = (const float*)d_in[3];
  const float* b1    = (const float*)d_in[4];
  const float* gamma = (const float*)d_in[5];
  const float* beta  = (const float*)d_in[6];
  const float* W2    = (const float*)d_in[7];
  const float* b2    = (const float*)d_in[8];

  float* out    = (float*)d_out;               // [N,64]
  float* hidden = out + (size_t)GN * OUTC;     // [N,128]

  float*          ws    = (float*)d_ws;
  unsigned*       h1b   = (unsigned*)(ws + OFF_H1);
  unsigned*       h2b   = (unsigned*)(ws + OFF_H2);
  float*          dinv1 = ws + OFF_DINV1;
  float*          dinv2 = ws + OFF_DINV2;
  int*            row1  = (int*)(ws + OFF_ROW1);
  int*            row2  = (int*)(ws + OFF_ROW2);
  int*            hist  = (int*)(ws + OFF_HIST);
  int*            tot   = (int*)(ws + OFF_TOT);
  int*            bbase = (int*)(ws + OFF_BBASE);
  float*          bnbuf = ws + OFF_BN;
  float*          part  = ws + OFF_PART;
  float*          partA = ws + OFF_HIST;       // aliases hist (dead after p1scat)
  int*            src1  = (int*)(ws + OFF_SRC1);
  int*            src2  = (int*)(ws + OFF_SRC2);
  int*            pb1   = (int*)h2b;
  int*            pb2   = pb1 + GE;

  p1hist_kernel<<<dim3(NW, 2), 256, 0, stream>>>(e1, e2, hist);
  histscanA_kernel<<<dim3(NBK, 2), 256, 0, stream>>>(hist, tot);
  histscanB_kernel<<<1, 256, 0, stream>>>(tot, bbase);
  p1scat_kernel<<<dim3(NW, 2), 256, 0, stream>>>(e1, e2, hist, bbase, pb1, pb2);
  p2sort_kernel<<<dim3(NBK, 2), 256, 0, stream>>>(pb1, pb2, bbase,
                                                  row1, row2, dinv1, dinv2, src1, src2);

  gemm1_kernel<<<(GN + 63) / 64, 256, 0, stream>>>(x, W1, dinv1,
                                                   (unsigned short*)h1b);
  agg1_kernel<<<A1B, 256, 0, stream>>>(h1b, row1, src1, dinv1, b1, hidden, part);

  bn_reduceA_kernel<<<64, 256, 0, stream>>>(part, partA);
  bn_final_kernel<<<1, 128, 0, stream>>>(partA, gamma, beta, bnbuf, bnbuf + 128);

  gemm2_kernel<<<(GN + 63) / 64, 256, 0, stream>>>(hidden, W2, bnbuf, bnbuf + 128,
                                                   dinv2, (unsigned short*)h2b);
  agg2_kernel<<<(GN * 64 + 255) / 256, 256, 0, stream>>>(
      (const unsigned short*)h2b, row2, src2, dinv2, b2, out);
}